// Round 11
// baseline (3198.649 us; speedup 1.0000x reference)
//
#include <hip/hip_runtime.h>
#include <hip/hip_bf16.h>

constexpr int kB  = 16;
constexpr int kN  = 1024;
constexpr int kH  = 64;
constexpr int kNB = 64;
constexpr int kNT = 16;   // kN / kNB

typedef float f4 __attribute__((ext_vector_type(4)));

// complex helpers ------------------------------------------------------------
__device__ __forceinline__ float2 cmul(float2 a, float2 b) {
  return make_float2(a.x * b.x - a.y * b.y, a.x * b.y + a.y * b.x);
}
__device__ __forceinline__ float2 cfma(float2 a, float2 b, float2 acc) {   // acc + a*b
  acc.x = fmaf(a.x, b.x, fmaf(-a.y, b.y, acc.x));
  acc.y = fmaf(a.x, b.y, fmaf( a.y, b.x, acc.y));
  return acc;
}
__device__ __forceinline__ float2 cnfma(float2 a, float2 b, float2 acc) {  // acc - a*b
  acc.x = fmaf(-a.x, b.x, fmaf( a.y, b.y, acc.x));
  acc.y = fmaf(-a.x, b.y, fmaf(-a.y, b.x, acc.y));
  return acc;
}
__device__ __forceinline__ float2 cinv(float2 p) {
  float d = 1.0f / (p.x * p.x + p.y * p.y);
  return make_float2(p.x * d, -p.y * d);
}
__device__ __forceinline__ float2 csel(bool c, float2 a, float2 b) {
  return c ? a : b;
}

// ---------------------------------------------------------------------------
// LDS layouts. TileLds 35840 B; PivSmem 37376 B; union 37376 B -> 4 blk/CU.
// ---------------------------------------------------------------------------
struct TileLds {
  f4 Ar[64][9];
  f4 Ai[64][9];
  f4 Br[32][17];
  f4 Bi[32][17];
};

struct PivSmem {
  float2 P[kNB][kNB + 1];
  float2 Cst[kNB][4];    // col panel (old values)
  float2 Rst[4][kNB];    // row panel (old values)
};

// update blocks use tile then M (transpose bounce); updpiv adds piv path.
union UpdPivSmem {
  TileLds tile;
  float2  M[64][66];     // 33792 B
  PivSmem piv;
};

// Stage one K=32 chunk directly global -> LDS (chunk 0 path).
__device__ __forceinline__ void stage_tiles(
    TileLds& L, int t,
    const float* __restrict__ Agr, const float* __restrict__ Agi, int astride,
    const float* __restrict__ Bgr, const float* __restrict__ Bgi, int bstride)
{
  #pragma unroll
  for (int q = 0; q < 2; ++q) {
    int e = q * 256 + t;
    int ra = e >> 3, ca = e & 7;        // A: 64 x 8 f4
    L.Ar[ra][ca] = *(const f4*)(Agr + (size_t)ra * astride + ca * 4);
    L.Ai[ra][ca] = *(const f4*)(Agi + (size_t)ra * astride + ca * 4);
    int rb = e >> 4, cb = e & 15;       // B: 32 x 16 f4
    L.Br[rb][cb] = *(const f4*)(Bgr + (size_t)rb * bstride + cb * 4);
    L.Bi[rb][cb] = *(const f4*)(Bgi + (size_t)rb * bstride + cb * 4);
  }
}

// T14 split: issue chunk-1 global loads into regs ...
__device__ __forceinline__ void prefetch_regs(
    int t,
    const float* __restrict__ Agr, const float* __restrict__ Agi, int astride,
    const float* __restrict__ Bgr, const float* __restrict__ Bgi, int bstride,
    f4 (&sar)[2], f4 (&sai)[2], f4 (&sbr)[2], f4 (&sbi)[2])
{
  #pragma unroll
  for (int q = 0; q < 2; ++q) {
    int e = q * 256 + t;
    int ra = e >> 3, ca = e & 7;
    sar[q] = *(const f4*)(Agr + (size_t)ra * astride + ca * 4);
    sai[q] = *(const f4*)(Agi + (size_t)ra * astride + ca * 4);
    int rb = e >> 4, cb = e & 15;
    sbr[q] = *(const f4*)(Bgr + (size_t)rb * bstride + cb * 4);
    sbi[q] = *(const f4*)(Bgi + (size_t)rb * bstride + cb * 4);
  }
}

// ... then write them to LDS after the barrier.
__device__ __forceinline__ void regs_to_lds(
    TileLds& L, int t,
    const f4 (&sar)[2], const f4 (&sai)[2],
    const f4 (&sbr)[2], const f4 (&sbi)[2])
{
  #pragma unroll
  for (int q = 0; q < 2; ++q) {
    int e = q * 256 + t;
    int ra = e >> 3, ca = e & 7;
    L.Ar[ra][ca] = sar[q]; L.Ai[ra][ca] = sai[q];
    int rb = e >> 4, cb = e & 15;
    L.Br[rb][cb] = sbr[q]; L.Bi[rb][cb] = sbi[q];
  }
}

__device__ __forceinline__ void cgemm_tile(
    const TileLds& L, int r0, int c0q, float (&cr)[4][4], float (&ci)[4][4])
{
  #pragma unroll 2
  for (int mq = 0; mq < 8; ++mq) {
    f4 ar[4], ai[4];
    #pragma unroll
    for (int i = 0; i < 4; ++i) {
      ar[i] = L.Ar[r0 + i][mq];
      ai[i] = L.Ai[r0 + i][mq];
    }
    #pragma unroll
    for (int mm = 0; mm < 4; ++mm) {
      f4 br = L.Br[mq * 4 + mm][c0q];
      f4 bi = L.Bi[mq * 4 + mm][c0q];
      #pragma unroll
      for (int i = 0; i < 4; ++i) {
        float a_r = ar[i][mm], a_i = ai[i][mm];
        #pragma unroll
        for (int j = 0; j < 4; ++j) {
          cr[i][j] = fmaf(a_r, br[j], fmaf(-a_i, bi[j], cr[i][j]));
          ci[i][j] = fmaf(a_r, bi[j], fmaf( a_i, br[j], ci[i][j]));
        }
      }
    }
  }
}

// ---------------------------------------------------------------------------
// Kernel 1: per-row MLPs (env & omega), gamma, decohered, omega staging.
// ---------------------------------------------------------------------------
__global__ __launch_bounds__(64) void rows_kernel(
    const float* __restrict__ gene, const float* __restrict__ coh,
    const float* __restrict__ gbase,
    const float* __restrict__ ew1, const float* __restrict__ eb1,
    const float* __restrict__ ew2, const float* __restrict__ eb2,
    const float* __restrict__ ow1, const float* __restrict__ ob1,
    const float* __restrict__ ow2, const float* __restrict__ ob2,
    float* __restrict__ out_dec, float* __restrict__ out_gamma,
    float* __restrict__ ws_omega)
{
  int row = blockIdx.x;          // b*kN + n
  int n   = row & (kN - 1);
  int t   = threadIdx.x;         // 0..63
  float g = gene[(size_t)row * kH + t];

  float s = g;
  #pragma unroll
  for (int off = 32; off >= 1; off >>= 1) s += __shfl_xor(s, off);
  float classical = s * (1.0f / kH);

  bool isEnv = t < 32;
  int  j     = isEnv ? t : (t - 32);
  const float* w1 = isEnv ? ew1 : ow1;
  float acc = isEnv ? eb1[j] : ob1[j];
  #pragma unroll
  for (int h = 0; h < kH; ++h) {
    float gh = __shfl(g, h);
    acc = fmaf(gh, w1[h * 32 + j], acc);
  }
  float sl   = acc * (1.0f / (1.0f + expf(-acc)));   // silu
  float term = sl * (isEnv ? ew2[j] : ow2[j]);
  #pragma unroll
  for (int off = 16; off >= 1; off >>= 1) term += __shfl_xor(term, off);
  float env_sum = __shfl(term, 0);
  float om_sum  = __shfl(term, 32);

  float env   = 1.0f / (1.0f + expf(-(env_sum + eb2[0])));
  float gamma = (1.0f / (1.0f + expf(-gbase[n]))) * (1.0f + env);

  float dec = (1.0f - gamma) * coh[(size_t)row * kH + t] + gamma * classical;
  out_dec[(size_t)row * kH + t] = dec;
  if (t == 0)  out_gamma[row] = gamma;
  if (t == 63) ws_omega[row]  = om_sum + ob2[0];
}

// ---------------------------------------------------------------------------
// Kernel 2 (v2, two-stage): cell mean + cosine-sim softmax -> state_probs.
// Stage 1: 16x16 blocks, each reduces 64 rows x 64 h -> partial.
// Stage 2: 16 blocks x 64 thr finish the 16-way reduce + softmax tail.
// (round-10 rocprof: single-stage probs = 73 us at 0.24% VALUBusy --
//  16-block parallelism starvation, not bytes.)
// ---------------------------------------------------------------------------
__global__ __launch_bounds__(256) void probs1_kernel(
    const float* __restrict__ gene, float* __restrict__ prt)
{
  __shared__ float red[256];
  int b = blockIdx.x, s = blockIdx.y, t = threadIdx.x;
  int h = t & 63, q = t >> 6;
  const float* gp = gene + ((size_t)b * kN + s * 64 + q * 16) * kH + h;
  float sum = 0.0f;
  #pragma unroll
  for (int i = 0; i < 16; ++i) sum += gp[(size_t)i * kH];
  red[t] = sum;
  __syncthreads();
  if (t < 64)
    prt[(b * 16 + s) * 64 + t] = red[t] + red[t + 64] + red[t + 128] + red[t + 192];
}

__global__ __launch_bounds__(64) void probs2_kernel(
    const float* __restrict__ prt, const float* __restrict__ emb,
    float* __restrict__ outp)
{
  __shared__ float cell[64];
  int b = blockIdx.x, t = threadIdx.x;
  float s = 0.0f;
  #pragma unroll
  for (int i = 0; i < 16; ++i) s += prt[(b * 16 + i) * 64 + t];
  cell[t] = s * (1.0f / kN);
  __syncthreads();
  if (t == 0) {
    float nc = 0.0f;
    for (int x = 0; x < 64; ++x) nc += cell[x] * cell[x];
    nc = fmaxf(sqrtf(nc), 1e-12f);
    float l[2];
    for (int s2 = 0; s2 < 2; ++s2) {
      float ne = 0.0f, dot = 0.0f;
      for (int x = 0; x < 64; ++x) { float e = emb[s2 * 64 + x]; ne += e * e; }
      ne = fmaxf(sqrtf(ne), 1e-12f);
      for (int x = 0; x < 64; ++x) dot += (cell[x] / nc) * (emb[s2 * 64 + x] / ne);
      l[s2] = dot * 10.0f;   // /0.1
    }
    float m  = fmaxf(l[0], l[1]);
    float e0 = expf(l[0] - m), e1 = expf(l[1] - m);
    outp[b * 2 + 0] = e0 / (e0 + e1);
    outp[b * 2 + 1] = e1 / (e0 + e1);
  }
}

// ---------------------------------------------------------------------------
// Kernel 3: omega_mean per batch.
// ---------------------------------------------------------------------------
__global__ __launch_bounds__(256) void omean_kernel(
    const float* __restrict__ om, float* __restrict__ omm)
{
  __shared__ float red[256];
  int b = blockIdx.x, t = threadIdx.x;
  float s = om[b * kN + t] + om[b * kN + t + 256] + om[b * kN + t + 512] + om[b * kN + t + 768];
  red[t] = s;
  __syncthreads();
  for (int off = 128; off >= 1; off >>= 1) {
    if (t < off) red[t] += red[t + off];
    __syncthreads();
  }
  if (t == 0) omm[b] = red[0] * (1.0f / kN);
}

// ---------------------------------------------------------------------------
// Kernel 4a: H_sym (fp32).  4b: A = w*I - H_sym (+ i*eta on diag), f4 stores.
// ---------------------------------------------------------------------------
__global__ __launch_bounds__(256) void hs_kernel(
    const float* __restrict__ Hm, float* __restrict__ Hs)
{
  int idx = blockIdx.x * 256 + threadIdx.x;
  int i = idx >> 10, j = idx & 1023;
  Hs[idx] = 0.5f * (Hm[i * kN + j] + Hm[j * kN + i]);
}

__global__ __launch_bounds__(256) void build_kernel(
    const float* __restrict__ Hs, const float* __restrict__ omm,
    float* __restrict__ Are, float* __restrict__ Aim, int b0)
{
  int bb = blockIdx.y;
  int e = blockIdx.x * 256 + threadIdx.x;     // f4 index into NN/4
  int i = e >> 8, j4 = e & 255;               // row, f4 column
  float wr = omm[b0 + bb];
  f4 h = *(const f4*)(Hs + (size_t)e * 4);
  f4 re, im;
  #pragma unroll
  for (int c = 0; c < 4; ++c) {               // branchless diag, static idx
    bool d = (j4 * 4 + c == i);
    re[c] = (d ? wr : 0.0f) - h[c];
    im[c] = d ? 0.01f : 0.0f;
  }
  *(f4*)(Are + (size_t)bb * kN * kN + (size_t)e * 4) = re;
  *(f4*)(Aim + (size_t)bb * kN * kN + (size_t)e * 4) = im;
}

// ---------------------------------------------------------------------------
// Pivot-block inverse device body: rank-4 blocked Gauss-Jordan, symmetrized
// output (round-10 proven; exact E symmetry required by the mirror scheme).
// ---------------------------------------------------------------------------
__device__ void pivotinv_dev(
    PivSmem& S,
    const float* __restrict__ Are, const float* __restrict__ Aim,
    float* __restrict__ Pro, float* __restrict__ Pio, int kstep, int bb, int t)
{
  size_t base = (size_t)bb * kN * kN + (size_t)(kstep * kNB) * kN + kstep * kNB;

  #pragma unroll
  for (int q = 0; q < 16; ++q) {
    int e = q * 256 + t;
    int r = e >> 6, c = e & 63;
    S.P[r][c] = make_float2(Are[base + (size_t)r * kN + c],
                            Aim[base + (size_t)r * kN + c]);
  }
  __syncthreads();

  const int c = t & 63;        // thread-fixed column
  const int w = t >> 6;        // 0..3
  const int cq = c & 3;        // panel-local column when cinP (p0 % 4 == 0)

  for (int ps = 0; ps < 16; ++ps) {
    const int p0 = ps * 4;
    S.Cst[t >> 2][t & 3]  = S.P[t >> 2][p0 + (t & 3)];
    S.Rst[t >> 6][t & 63] = S.P[p0 + (t >> 6)][t & 63];
    __syncthreads();

    float2 E[4][4];
    #pragma unroll
    for (int r = 0; r < 4; ++r)
      #pragma unroll
      for (int q = 0; q < 4; ++q) E[r][q] = S.Rst[r][p0 + q];
    #pragma unroll
    for (int s4 = 0; s4 < 4; ++s4) {
      float2 ip = cinv(E[s4][s4]);
      #pragma unroll
      for (int cc = 0; cc < 4; ++cc)
        if (cc != s4) E[s4][cc] = cmul(E[s4][cc], ip);
      #pragma unroll
      for (int i = 0; i < 4; ++i)
        if (i != s4) {
          float2 f = E[i][s4];
          #pragma unroll
          for (int cc = 0; cc < 4; ++cc)
            if (cc != s4) E[i][cc] = cnfma(f, E[s4][cc], E[i][cc]);
          E[i][s4] = cmul(make_float2(-f.x, -f.y), ip);
        }
      E[s4][s4] = ip;
    }

    float2 Rp[4];
    #pragma unroll
    for (int r = 0; r < 4; ++r) {
      float2 acc = cmul(E[r][0], S.Rst[0][c]);
      acc = cfma(E[r][1], S.Rst[1][c], acc);
      acc = cfma(E[r][2], S.Rst[2][c], acc);
      acc = cfma(E[r][3], S.Rst[3][c], acc);
      Rp[r] = acc;
    }

    const bool cinP = (c >= p0) && (c < p0 + 4);
    float2 Ecol[4];
    #pragma unroll
    for (int r = 0; r < 4; ++r) {
      float2 a = csel(cq & 1, E[r][1], E[r][0]);
      float2 b = csel(cq & 1, E[r][3], E[r][2]);
      Ecol[r] = csel(cq & 2, b, a);
    }
    float2 ra  = csel(w & 1, Rp[1], Rp[0]);
    float2 rb  = csel(w & 1, Rp[3], Rp[2]);
    float2 Rpw = csel(w & 2, rb, ra);
    float2 ea  = csel(w & 1, Ecol[1], Ecol[0]);
    float2 eb  = csel(w & 1, Ecol[3], Ecol[2]);
    float2 Ecw = csel(w & 2, eb, ea);
    float2 inPval = csel(cinP, Ecw, Rpw);

    #pragma unroll
    for (int qq = 0; qq < 16; ++qq) {
      int i = w + 4 * qq;
      const f4* fp = (const f4*)(&S.Cst[i][0]);   // broadcast (i uniform per wave)
      f4 f01 = fp[0], f23 = fp[1];
      float2 f0 = make_float2(f01.x, f01.y), f1 = make_float2(f01.z, f01.w);
      float2 f2 = make_float2(f23.x, f23.y), f3 = make_float2(f23.z, f23.w);
      float2 old = S.P[i][c];
      float2 g = old;
      g = cnfma(f0, Rp[0], g);
      g = cnfma(f1, Rp[1], g);
      g = cnfma(f2, Rp[2], g);
      g = cnfma(f3, Rp[3], g);
      float2 cp = cmul(f0, Ecol[0]);
      cp = cfma(f1, Ecol[1], cp);
      cp = cfma(f2, Ecol[2], cp);
      cp = cfma(f3, Ecol[3], cp);
      cp.x = -cp.x; cp.y = -cp.y;
      float2 other = csel(cinP, cp, g);
      float2 res   = csel(qq == ps, inPval, other);
      S.P[i][c] = res;
    }
    __syncthreads();
  }

  // SYMMETRIZED write-out: Pout[r][c] = 0.5*(P[r][c] + P[c][r]).
  int pbase = bb * kNB * kNB;
  #pragma unroll
  for (int q = 0; q < 16; ++q) {
    int e = q * 256 + t;
    int r = e >> 6, cc = e & 63;
    float2 v  = S.P[r][cc];
    float2 vt = S.P[cc][r];
    Pro[pbase + e] = 0.5f * (v.x + vt.x);
    Pio[pbase + e] = 0.5f * (v.y + vt.y);
  }
}

// Standalone pivotinv (used for k=0 of each chunk).
__global__ __launch_bounds__(256) void pivotinv_kernel(
    const float* __restrict__ Are, const float* __restrict__ Aim,
    float* __restrict__ Pro, float* __restrict__ Pio, int kstep)
{
  __shared__ PivSmem S;
  pivotinv_dev(S, Are, Aim, Pro, Pio, kstep, blockIdx.x, threadIdx.x);
}

// ---------------------------------------------------------------------------
// Kernel 6: column block in place: A[rt,k] <- -(A[rt,k] @ Pinv)  (rt != k).
// ---------------------------------------------------------------------------
__global__ __launch_bounds__(256) void colgemm_kernel(
    float* __restrict__ Are, float* __restrict__ Aim,
    const float* __restrict__ Pr, const float* __restrict__ Pi, int kstep)
{
  int rt = blockIdx.x;
  if (rt == kstep) return;
  int bb = blockIdx.y, t = threadIdx.x;
  size_t abase = (size_t)bb * kN * kN + (size_t)(rt * kNB) * kN + kstep * kNB;
  int pbase = bb * kNB * kNB;
  __shared__ TileLds L;
  float cr[4][4] = {}, ci[4][4] = {};
  int r0 = (t >> 4) * 4, c0q = t & 15;

  stage_tiles(L, t, Are + abase, Aim + abase, kN,
              Pr + pbase, Pi + pbase, kNB);
  __syncthreads();

  f4 sar[2], sai[2], sbr[2], sbi[2];
  prefetch_regs(t, Are + abase + 32, Aim + abase + 32, kN,
                Pr + pbase + 32 * kNB, Pi + pbase + 32 * kNB, kNB,
                sar, sai, sbr, sbi);
  cgemm_tile(L, r0, c0q, cr, ci);
  __syncthreads();

  regs_to_lds(L, t, sar, sai, sbr, sbi);
  __syncthreads();
  cgemm_tile(L, r0, c0q, cr, ci);

  #pragma unroll
  for (int i = 0; i < 4; ++i) {
    size_t idx = abase + (size_t)(r0 + i) * kN + c0q * 4;
    *(f4*)(Are + idx) = (f4){-cr[i][0], -cr[i][1], -cr[i][2], -cr[i][3]};
    *(f4*)(Aim + idx) = (f4){-ci[i][0], -ci[i][1], -ci[i][2], -ci[i][3]};
  }
}

// ---------------------------------------------------------------------------
// Trailing-update pair body (round-10 proven): pair idx in lower triangle,
// RMW own block, mirror transposed tile into the upper block (eps-signed).
// ---------------------------------------------------------------------------
__device__ void update_pair_dev(
    UpdPivSmem& S, float* __restrict__ Are, float* __restrict__ Aim,
    int kstep, int idx, int bb, int t)
{
  // decode idx -> (a, b) with a >= b over 15 indices (0..14)
  int a = (int)((sqrtf(8.0f * (float)idx + 1.0f) - 1.0f) * 0.5f);
  while ((a + 1) * (a + 2) / 2 <= idx) ++a;
  while (a * (a + 1) / 2 > idx) --a;
  int b = idx - a * (a + 1) / 2;
  int rt = a + (a >= kstep);
  int ct = b + (b >= kstep);

  size_t NNb     = (size_t)bb * kN * kN;
  size_t colbase = NNb + (size_t)(rt * kNB) * kN + kstep * kNB;
  size_t rowbase = NNb + (size_t)(kstep * kNB) * kN + ct * kNB;
  size_t cb      = NNb + (size_t)(rt * kNB) * kN + ct * kNB;
  float cr[4][4] = {}, ci[4][4] = {};
  int r0 = (t >> 4) * 4, c0q = t & 15;

  stage_tiles(S.tile, t, Are + colbase, Aim + colbase, kN,
              Are + rowbase, Aim + rowbase, kN);
  __syncthreads();

  f4 sar[2], sai[2], sbr[2], sbi[2];
  prefetch_regs(t, Are + colbase + 32, Aim + colbase + 32, kN,
                Are + rowbase + (size_t)32 * kN,
                Aim + rowbase + (size_t)32 * kN, kN,
                sar, sai, sbr, sbi);
  cgemm_tile(S.tile, r0, c0q, cr, ci);
  __syncthreads();

  regs_to_lds(S.tile, t, sar, sai, sbr, sbi);
  __syncthreads();
  cgemm_tile(S.tile, r0, c0q, cr, ci);

  // RMW own (lower/diag) block, keep the new values for the mirror
  f4 vr4[4], vi4[4];
  #pragma unroll
  for (int i = 0; i < 4; ++i) {
    size_t gidx = cb + (size_t)(r0 + i) * kN + c0q * 4;
    f4 vr = *(const f4*)(Are + gidx);
    f4 vi = *(const f4*)(Aim + gidx);
    vr += (f4){cr[i][0], cr[i][1], cr[i][2], cr[i][3]};
    vi += (f4){ci[i][0], ci[i][1], ci[i][2], ci[i][3]};
    *(f4*)(Are + gidx) = vr;
    *(f4*)(Aim + gidx) = vi;
    vr4[i] = vr; vi4[i] = vi;
  }

  if (rt != ct) {
    float eps = ((rt < kstep) == (ct < kstep)) ? 1.0f : -1.0f;
    __syncthreads();                     // all tile-LDS reads complete
    #pragma unroll
    for (int i = 0; i < 4; ++i)
      #pragma unroll
      for (int j = 0; j < 4; ++j)
        S.M[c0q * 4 + j][r0 + i] =
            make_float2(eps * vr4[i][j], eps * vi4[i][j]);
    __syncthreads();
    size_t mb = NNb + (size_t)(ct * kNB) * kN + rt * kNB;   // mirror block
    #pragma unroll
    for (int q = 0; q < 4; ++q) {        // 1024 e-values: full 64 rows
      int e = q * 256 + t;
      int r = e >> 4, c4 = e & 15;
      float2 m0 = S.M[r][c4 * 4 + 0], m1 = S.M[r][c4 * 4 + 1];
      float2 m2 = S.M[r][c4 * 4 + 2], m3 = S.M[r][c4 * 4 + 3];
      *(f4*)(Are + mb + (size_t)r * kN + c4 * 4) = (f4){m0.x, m1.x, m2.x, m3.x};
      *(f4*)(Aim + mb + (size_t)r * kN + c4 * 4) = (f4){m0.y, m1.y, m2.y, m3.y};
    }
  }
}

// ---------------------------------------------------------------------------
// Kernel 7a (look-ahead): ONLY the (k+1,k+1) diag pair -- the sole dependency
// of pivotinv(k+1). Runs right after colgemm so pivotinv can overlap the rest.
// ---------------------------------------------------------------------------
__global__ __launch_bounds__(256) void updiag_kernel(
    float* __restrict__ Are, float* __restrict__ Aim, int kstep)
{
  __shared__ UpdPivSmem S;
  int idxd = kstep * (kstep + 1) / 2 + kstep;   // a=b=kstep -> rt=ct=kstep+1
  update_pair_dev(S, Are, Aim, kstep, idxd, blockIdx.y, threadIdx.x);
}

// ---------------------------------------------------------------------------
// Kernel 7b: remaining update pairs FUSED with pivotinv(k+1).
// x == gridDim.x-1 (when withpiv) -> pivotinv block; else update pair,
// skipping skipidx (the diag pair already done by updiag).
// ---------------------------------------------------------------------------
__global__ __launch_bounds__(256) void updpiv_kernel(
    float* __restrict__ Are, float* __restrict__ Aim,
    float* __restrict__ Prn, float* __restrict__ Pin,
    int kstep, int skipidx, int withpiv)
{
  __shared__ UpdPivSmem S;
  int x = blockIdx.x, bb = blockIdx.y, t = threadIdx.x;
  if (withpiv && x == (int)gridDim.x - 1) {
    pivotinv_dev(S.piv, Are, Aim, Prn, Pin, kstep + 1, bb, t);
    return;
  }
  int idx = x + ((skipidx >= 0 && x >= skipidx) ? 1 : 0);
  update_pair_dev(S, Are, Aim, kstep, idx, bb, t);
}

// ---------------------------------------------------------------------------
// Kernel 8: row fixup A[k,j] = Pinv @ A[k,j]_old (j != k); diag block = Pinv.
// ---------------------------------------------------------------------------
__global__ __launch_bounds__(256) void rowfix_kernel(
    float* __restrict__ Are, float* __restrict__ Aim,
    const float* __restrict__ Pr, const float* __restrict__ Pi, int kstep)
{
  int ct = blockIdx.x, bb = blockIdx.y, t = threadIdx.x;
  int pbase = bb * kNB * kNB;
  size_t rb = (size_t)bb * kN * kN + (size_t)(kstep * kNB) * kN + ct * kNB;
  if (ct == kstep) {
    for (int e = t; e < kNB * kNB / 4; e += 256) {
      int r = e >> 4, c4 = e & 15;
      *(f4*)(Are + rb + (size_t)r * kN + c4 * 4) = *(const f4*)(Pr + pbase + e * 4);
      *(f4*)(Aim + rb + (size_t)r * kN + c4 * 4) = *(const f4*)(Pi + pbase + e * 4);
    }
    return;
  }
  __shared__ TileLds L;
  float cr[4][4] = {}, ci[4][4] = {};
  int r0 = (t >> 4) * 4, c0q = t & 15;

  stage_tiles(L, t, Pr + pbase, Pi + pbase, kNB,
              Are + rb, Aim + rb, kN);
  __syncthreads();

  f4 sar[2], sai[2], sbr[2], sbi[2];
  prefetch_regs(t, Pr + pbase + 32, Pi + pbase + 32, kNB,
                Are + rb + (size_t)32 * kN, Aim + rb + (size_t)32 * kN, kN,
                sar, sai, sbr, sbi);
  cgemm_tile(L, r0, c0q, cr, ci);
  __syncthreads();

  regs_to_lds(L, t, sar, sai, sbr, sbi);
  __syncthreads();
  cgemm_tile(L, r0, c0q, cr, ci);

  #pragma unroll
  for (int i = 0; i < 4; ++i) {
    size_t idx = rb + (size_t)(r0 + i) * kN + c0q * 4;
    *(f4*)(Are + idx) = (f4){cr[i][0], cr[i][1], cr[i][2], cr[i][3]};
    *(f4*)(Aim + idx) = (f4){ci[i][0], ci[i][1], ci[i][2], ci[i][3]};
  }
}

// ---------------------------------------------------------------------------
// Kernel 9: |inv| -> f32 output (one chunk; out already offset by b0). f4 I/O.
// ---------------------------------------------------------------------------
__global__ __launch_bounds__(256) void abs_kernel(
    const float* __restrict__ Are, const float* __restrict__ Aim,
    float* __restrict__ outp)
{
  size_t e = (size_t)blockIdx.x * 256 + threadIdx.x;
  f4 re = *(const f4*)(Are + e * 4);
  f4 im = *(const f4*)(Aim + e * 4);
  f4 o;
  #pragma unroll
  for (int c = 0; c < 4; ++c) o[c] = sqrtf(re[c] * re[c] + im[c] * im[c]);
  *(f4*)(outp + e * 4) = o;
}

// ---------------------------------------------------------------------------
extern "C" void kernel_launch(void* const* d_in, const int* in_sizes, int n_in,
                              void* d_out, int out_size, void* d_ws, size_t ws_size,
                              hipStream_t stream)
{
  const float* gene  = (const float*)d_in[0];
  const float* coh   = (const float*)d_in[1];
  const float* emb   = (const float*)d_in[2];
  const float* gbase = (const float*)d_in[3];
  const float* ew1   = (const float*)d_in[4];
  const float* eb1   = (const float*)d_in[5];
  const float* ew2   = (const float*)d_in[6];
  const float* eb2   = (const float*)d_in[7];
  const float* ow1   = (const float*)d_in[8];
  const float* ob1   = (const float*)d_in[9];
  const float* ow2   = (const float*)d_in[10];
  const float* ob2   = (const float*)d_in[11];
  const float* Hm    = (const float*)d_in[12];

  float* out       = (float*)d_out;
  float* out_probs = out;                                  // 16*2
  float* out_dec   = out + 32;                             // 16*1024*64
  float* out_gamma = out + 32 + 1048576;                   // 16*1024
  float* out_prop  = out + 32 + 1048576 + 16384;           // 16*1024*1024

  // --- workspace sizing: chunk batches to fit ws_size -----------------------
  const size_t NN      = (size_t)kN * kN;                 // 1,048,576
  const size_t PB      = (size_t)kNB * kNB;               // 4096
  const size_t perB    = 2 * NN + 4 * PB;                 // A(re,im) + P parity x2
  const size_t fixedF  = NN + (size_t)kB * kN + 16 + (size_t)kB * 16 * 64;
  size_t availF = ws_size / 4;
  int chunk = 1;
  if (availF > fixedF + perB) {
    size_t c = (availF - fixedF) / perB;
    chunk = (int)(c > 16 ? 16 : c);
    if (chunk < 1) chunk = 1;
  }

  float* Are  = (float*)d_ws;
  float* Aim  = Are + (size_t)chunk * NN;
  float* Pr0  = Aim + (size_t)chunk * NN;
  float* Pi0  = Pr0 + (size_t)chunk * PB;
  float* Pr1  = Pi0 + (size_t)chunk * PB;
  float* Pi1  = Pr1 + (size_t)chunk * PB;
  float* Hs   = Pi1 + (size_t)chunk * PB;
  float* wsom = Hs  + NN;
  float* womm = wsom + (size_t)kB * kN;
  float* prt  = womm + 16;                                // 16*16*64 partials

  rows_kernel<<<kB * kN, 64, 0, stream>>>(gene, coh, gbase, ew1, eb1, ew2, eb2,
                                          ow1, ob1, ow2, ob2,
                                          out_dec, out_gamma, wsom);
  probs1_kernel<<<dim3(kB, 16), 256, 0, stream>>>(gene, prt);
  probs2_kernel<<<kB, 64, 0, stream>>>(prt, emb, out_probs);
  omean_kernel<<<kB, 256, 0, stream>>>(wsom, womm);
  hs_kernel<<<(kN * kN) / 256, 256, 0, stream>>>(Hm, Hs);

  for (int b0 = 0; b0 < kB; b0 += chunk) {
    int c = (b0 + chunk <= kB) ? chunk : (kB - b0);
    build_kernel<<<dim3((kN * kN) / 1024, c), 256, 0, stream>>>(Hs, womm, Are, Aim, b0);
    pivotinv_kernel<<<c, 256, 0, stream>>>(Are, Aim, Pr0, Pi0, 0);
    for (int k = 0; k < kNT; ++k) {
      float* Prc = (k & 1) ? Pr1 : Pr0;
      float* Pic = (k & 1) ? Pi1 : Pi0;
      float* Prn = (k & 1) ? Pr0 : Pr1;
      float* Pin = (k & 1) ? Pi0 : Pi1;
      colgemm_kernel<<<dim3(kNT, c), 256, 0, stream>>>(Are, Aim, Prc, Pic, k);
      if (k < kNT - 1) {
        int skip = k * (k + 1) / 2 + k;
        updiag_kernel<<<dim3(1, c), 256, 0, stream>>>(Are, Aim, k);
        updpiv_kernel<<<dim3(120, c), 256, 0, stream>>>(Are, Aim, Prn, Pin,
                                                        k, skip, 1);
      } else {
        updpiv_kernel<<<dim3(120, c), 256, 0, stream>>>(Are, Aim, Prn, Pin,
                                                        k, -1, 0);
      }
      rowfix_kernel<<<dim3(kNT, c), 256, 0, stream>>>(Are, Aim, Prc, Pic, k);
    }
    abs_kernel<<<c * (kN * kN / 1024), 256, 0, stream>>>(
        Are, Aim, out_prop + (size_t)b0 * NN);
  }
}

// Round 12
// 2293.234 us; speedup vs baseline: 1.3948x; 1.3948x over previous
//
#include <hip/hip_runtime.h>
#include <hip/hip_bf16.h>

constexpr int kB  = 16;
constexpr int kN  = 1024;
constexpr int kH  = 64;
constexpr int kNB = 64;
constexpr int kNT = 16;   // kN / kNB

typedef float f4 __attribute__((ext_vector_type(4)));

// complex helpers ------------------------------------------------------------
__device__ __forceinline__ float2 cmul(float2 a, float2 b) {
  return make_float2(a.x * b.x - a.y * b.y, a.x * b.y + a.y * b.x);
}
__device__ __forceinline__ float2 cfma(float2 a, float2 b, float2 acc) {   // acc + a*b
  acc.x = fmaf(a.x, b.x, fmaf(-a.y, b.y, acc.x));
  acc.y = fmaf(a.x, b.y, fmaf( a.y, b.x, acc.y));
  return acc;
}
__device__ __forceinline__ float2 cnfma(float2 a, float2 b, float2 acc) {  // acc - a*b
  acc.x = fmaf(-a.x, b.x, fmaf( a.y, b.y, acc.x));
  acc.y = fmaf(-a.x, b.y, fmaf(-a.y, b.x, acc.y));
  return acc;
}
__device__ __forceinline__ float2 cinv(float2 p) {
  float d = 1.0f / (p.x * p.x + p.y * p.y);
  return make_float2(p.x * d, -p.y * d);
}
__device__ __forceinline__ float2 csel(bool c, float2 a, float2 b) {
  return c ? a : b;
}

// ---------------------------------------------------------------------------
// LDS tile layout for 64x64 complex block-GEMMs. 35840 B.
// ---------------------------------------------------------------------------
struct TileLds {
  f4 Ar[64][9];
  f4 Ai[64][9];
  f4 Br[32][17];
  f4 Bi[32][17];
};

// Pivot-inverse LDS: P + single-buffered panels. 37376 B.
struct PivSmem {
  float2 P[kNB][kNB + 1];
  float2 Cst[kNB][4];    // col panel (old values)
  float2 Rst[4][kNB];    // row panel (old values)
};

union FusedSmem {
  TileLds tile;
  PivSmem piv;
};

// update_kernel LDS: GEMM tile, then reused as transpose bounce for mirror.
union UpdSmem {
  TileLds tile;
  float2  M[64][66];     // 33792 B <= 35840
};

// Stage one K=32 chunk directly global -> LDS (chunk 0 path).
__device__ __forceinline__ void stage_tiles(
    TileLds& L, int t,
    const float* __restrict__ Agr, const float* __restrict__ Agi, int astride,
    const float* __restrict__ Bgr, const float* __restrict__ Bgi, int bstride)
{
  #pragma unroll
  for (int q = 0; q < 2; ++q) {
    int e = q * 256 + t;
    int ra = e >> 3, ca = e & 7;        // A: 64 x 8 f4
    L.Ar[ra][ca] = *(const f4*)(Agr + (size_t)ra * astride + ca * 4);
    L.Ai[ra][ca] = *(const f4*)(Agi + (size_t)ra * astride + ca * 4);
    int rb = e >> 4, cb = e & 15;       // B: 32 x 16 f4
    L.Br[rb][cb] = *(const f4*)(Bgr + (size_t)rb * bstride + cb * 4);
    L.Bi[rb][cb] = *(const f4*)(Bgi + (size_t)rb * bstride + cb * 4);
  }
}

// T14 split: issue chunk-1 global loads into regs ...
__device__ __forceinline__ void prefetch_regs(
    int t,
    const float* __restrict__ Agr, const float* __restrict__ Agi, int astride,
    const float* __restrict__ Bgr, const float* __restrict__ Bgi, int bstride,
    f4 (&sar)[2], f4 (&sai)[2], f4 (&sbr)[2], f4 (&sbi)[2])
{
  #pragma unroll
  for (int q = 0; q < 2; ++q) {
    int e = q * 256 + t;
    int ra = e >> 3, ca = e & 7;
    sar[q] = *(const f4*)(Agr + (size_t)ra * astride + ca * 4);
    sai[q] = *(const f4*)(Agi + (size_t)ra * astride + ca * 4);
    int rb = e >> 4, cb = e & 15;
    sbr[q] = *(const f4*)(Bgr + (size_t)rb * bstride + cb * 4);
    sbi[q] = *(const f4*)(Bgi + (size_t)rb * bstride + cb * 4);
  }
}

// ... then write them to LDS after the barrier.
__device__ __forceinline__ void regs_to_lds(
    TileLds& L, int t,
    const f4 (&sar)[2], const f4 (&sai)[2],
    const f4 (&sbr)[2], const f4 (&sbi)[2])
{
  #pragma unroll
  for (int q = 0; q < 2; ++q) {
    int e = q * 256 + t;
    int ra = e >> 3, ca = e & 7;
    L.Ar[ra][ca] = sar[q]; L.Ai[ra][ca] = sai[q];
    int rb = e >> 4, cb = e & 15;
    L.Br[rb][cb] = sbr[q]; L.Bi[rb][cb] = sbi[q];
  }
}

__device__ __forceinline__ void cgemm_tile(
    const TileLds& L, int r0, int c0q, float (&cr)[4][4], float (&ci)[4][4])
{
  #pragma unroll 2
  for (int mq = 0; mq < 8; ++mq) {
    f4 ar[4], ai[4];
    #pragma unroll
    for (int i = 0; i < 4; ++i) {
      ar[i] = L.Ar[r0 + i][mq];
      ai[i] = L.Ai[r0 + i][mq];
    }
    #pragma unroll
    for (int mm = 0; mm < 4; ++mm) {
      f4 br = L.Br[mq * 4 + mm][c0q];
      f4 bi = L.Bi[mq * 4 + mm][c0q];
      #pragma unroll
      for (int i = 0; i < 4; ++i) {
        float a_r = ar[i][mm], a_i = ai[i][mm];
        #pragma unroll
        for (int j = 0; j < 4; ++j) {
          cr[i][j] = fmaf(a_r, br[j], fmaf(-a_i, bi[j], cr[i][j]));
          ci[i][j] = fmaf(a_r, bi[j], fmaf( a_i, br[j], ci[i][j]));
        }
      }
    }
  }
}

// ---------------------------------------------------------------------------
// Kernel 1: per-row MLPs (env & omega), gamma, decohered, omega staging.
// ---------------------------------------------------------------------------
__global__ __launch_bounds__(64) void rows_kernel(
    const float* __restrict__ gene, const float* __restrict__ coh,
    const float* __restrict__ gbase,
    const float* __restrict__ ew1, const float* __restrict__ eb1,
    const float* __restrict__ ew2, const float* __restrict__ eb2,
    const float* __restrict__ ow1, const float* __restrict__ ob1,
    const float* __restrict__ ow2, const float* __restrict__ ob2,
    float* __restrict__ out_dec, float* __restrict__ out_gamma,
    float* __restrict__ ws_omega)
{
  int row = blockIdx.x;          // b*kN + n
  int n   = row & (kN - 1);
  int t   = threadIdx.x;         // 0..63
  float g = gene[(size_t)row * kH + t];

  float s = g;
  #pragma unroll
  for (int off = 32; off >= 1; off >>= 1) s += __shfl_xor(s, off);
  float classical = s * (1.0f / kH);

  bool isEnv = t < 32;
  int  j     = isEnv ? t : (t - 32);
  const float* w1 = isEnv ? ew1 : ow1;
  float acc = isEnv ? eb1[j] : ob1[j];
  #pragma unroll
  for (int h = 0; h < kH; ++h) {
    float gh = __shfl(g, h);
    acc = fmaf(gh, w1[h * 32 + j], acc);
  }
  float sl   = acc * (1.0f / (1.0f + expf(-acc)));   // silu
  float term = sl * (isEnv ? ew2[j] : ow2[j]);
  #pragma unroll
  for (int off = 16; off >= 1; off >>= 1) term += __shfl_xor(term, off);
  float env_sum = __shfl(term, 0);
  float om_sum  = __shfl(term, 32);

  float env   = 1.0f / (1.0f + expf(-(env_sum + eb2[0])));
  float gamma = (1.0f / (1.0f + expf(-gbase[n]))) * (1.0f + env);

  float dec = (1.0f - gamma) * coh[(size_t)row * kH + t] + gamma * classical;
  out_dec[(size_t)row * kH + t] = dec;
  if (t == 0)  out_gamma[row] = gamma;
  if (t == 63) ws_omega[row]  = om_sum + ob2[0];
}

// ---------------------------------------------------------------------------
// Kernel 2 (two-stage): cell mean + cosine-sim softmax -> state_probs.
// Stage 1: 16x16 blocks reduce 64 rows each; stage 2: 16 blocks finish.
// (round-10 rocprof: single-stage probs = 73 us at 0.24% VALUBusy --
//  16-block parallelism starvation, not bytes.)
// ---------------------------------------------------------------------------
__global__ __launch_bounds__(256) void probs1_kernel(
    const float* __restrict__ gene, float* __restrict__ prt)
{
  __shared__ float red[256];
  int b = blockIdx.x, s = blockIdx.y, t = threadIdx.x;
  int h = t & 63, q = t >> 6;
  const float* gp = gene + ((size_t)b * kN + s * 64 + q * 16) * kH + h;
  float sum = 0.0f;
  #pragma unroll
  for (int i = 0; i < 16; ++i) sum += gp[(size_t)i * kH];
  red[t] = sum;
  __syncthreads();
  if (t < 64)
    prt[(b * 16 + s) * 64 + t] = red[t] + red[t + 64] + red[t + 128] + red[t + 192];
}

__global__ __launch_bounds__(64) void probs2_kernel(
    const float* __restrict__ prt, const float* __restrict__ emb,
    float* __restrict__ outp)
{
  __shared__ float cell[64];
  int b = blockIdx.x, t = threadIdx.x;
  float s = 0.0f;
  #pragma unroll
  for (int i = 0; i < 16; ++i) s += prt[(b * 16 + i) * 64 + t];
  cell[t] = s * (1.0f / kN);
  __syncthreads();
  if (t == 0) {
    float nc = 0.0f;
    for (int x = 0; x < 64; ++x) nc += cell[x] * cell[x];
    nc = fmaxf(sqrtf(nc), 1e-12f);
    float l[2];
    for (int s2 = 0; s2 < 2; ++s2) {
      float ne = 0.0f, dot = 0.0f;
      for (int x = 0; x < 64; ++x) { float e = emb[s2 * 64 + x]; ne += e * e; }
      ne = fmaxf(sqrtf(ne), 1e-12f);
      for (int x = 0; x < 64; ++x) dot += (cell[x] / nc) * (emb[s2 * 64 + x] / ne);
      l[s2] = dot * 10.0f;   // /0.1
    }
    float m  = fmaxf(l[0], l[1]);
    float e0 = expf(l[0] - m), e1 = expf(l[1] - m);
    outp[b * 2 + 0] = e0 / (e0 + e1);
    outp[b * 2 + 1] = e1 / (e0 + e1);
  }
}

// ---------------------------------------------------------------------------
// Kernel 3: omega_mean per batch.
// ---------------------------------------------------------------------------
__global__ __launch_bounds__(256) void omean_kernel(
    const float* __restrict__ om, float* __restrict__ omm)
{
  __shared__ float red[256];
  int b = blockIdx.x, t = threadIdx.x;
  float s = om[b * kN + t] + om[b * kN + t + 256] + om[b * kN + t + 512] + om[b * kN + t + 768];
  red[t] = s;
  __syncthreads();
  for (int off = 128; off >= 1; off >>= 1) {
    if (t < off) red[t] += red[t + off];
    __syncthreads();
  }
  if (t == 0) omm[b] = red[0] * (1.0f / kN);
}

// ---------------------------------------------------------------------------
// Kernel 4a: H_sym (fp32).  4b: A = w*I - H_sym (+ i*eta on diag), f4 stores.
// ---------------------------------------------------------------------------
__global__ __launch_bounds__(256) void hs_kernel(
    const float* __restrict__ Hm, float* __restrict__ Hs)
{
  int idx = blockIdx.x * 256 + threadIdx.x;
  int i = idx >> 10, j = idx & 1023;
  Hs[idx] = 0.5f * (Hm[i * kN + j] + Hm[j * kN + i]);
}

__global__ __launch_bounds__(256) void build_kernel(
    const float* __restrict__ Hs, const float* __restrict__ omm,
    float* __restrict__ Are, float* __restrict__ Aim, int b0)
{
  int bb = blockIdx.y;
  int e = blockIdx.x * 256 + threadIdx.x;     // f4 index into NN/4
  int i = e >> 8, j4 = e & 255;               // row, f4 column
  float wr = omm[b0 + bb];
  f4 h = *(const f4*)(Hs + (size_t)e * 4);
  f4 re, im;
  #pragma unroll
  for (int c = 0; c < 4; ++c) {               // branchless diag, static idx
    bool d = (j4 * 4 + c == i);
    re[c] = (d ? wr : 0.0f) - h[c];
    im[c] = d ? 0.01f : 0.0f;
  }
  *(f4*)(Are + (size_t)bb * kN * kN + (size_t)e * 4) = re;
  *(f4*)(Aim + (size_t)bb * kN * kN + (size_t)e * 4) = im;
}

// ---------------------------------------------------------------------------
// Pivot-block inverse device body: rank-4 blocked Gauss-Jordan, symmetrized
// output (round-10 proven; exact E symmetry required by the mirror scheme).
// ---------------------------------------------------------------------------
__device__ void pivotinv_dev(
    PivSmem& S,
    const float* __restrict__ Are, const float* __restrict__ Aim,
    float* __restrict__ Pro, float* __restrict__ Pio, int kstep, int bb, int t)
{
  size_t base = (size_t)bb * kN * kN + (size_t)(kstep * kNB) * kN + kstep * kNB;

  #pragma unroll
  for (int q = 0; q < 16; ++q) {
    int e = q * 256 + t;
    int r = e >> 6, c = e & 63;
    S.P[r][c] = make_float2(Are[base + (size_t)r * kN + c],
                            Aim[base + (size_t)r * kN + c]);
  }
  __syncthreads();

  const int c = t & 63;        // thread-fixed column
  const int w = t >> 6;        // 0..3
  const int cq = c & 3;        // panel-local column when cinP (p0 % 4 == 0)

  for (int ps = 0; ps < 16; ++ps) {
    const int p0 = ps * 4;
    S.Cst[t >> 2][t & 3]  = S.P[t >> 2][p0 + (t & 3)];
    S.Rst[t >> 6][t & 63] = S.P[p0 + (t >> 6)][t & 63];
    __syncthreads();

    float2 E[4][4];
    #pragma unroll
    for (int r = 0; r < 4; ++r)
      #pragma unroll
      for (int q = 0; q < 4; ++q) E[r][q] = S.Rst[r][p0 + q];
    #pragma unroll
    for (int s4 = 0; s4 < 4; ++s4) {
      float2 ip = cinv(E[s4][s4]);
      #pragma unroll
      for (int cc = 0; cc < 4; ++cc)
        if (cc != s4) E[s4][cc] = cmul(E[s4][cc], ip);
      #pragma unroll
      for (int i = 0; i < 4; ++i)
        if (i != s4) {
          float2 f = E[i][s4];
          #pragma unroll
          for (int cc = 0; cc < 4; ++cc)
            if (cc != s4) E[i][cc] = cnfma(f, E[s4][cc], E[i][cc]);
          E[i][s4] = cmul(make_float2(-f.x, -f.y), ip);
        }
      E[s4][s4] = ip;
    }

    float2 Rp[4];
    #pragma unroll
    for (int r = 0; r < 4; ++r) {
      float2 acc = cmul(E[r][0], S.Rst[0][c]);
      acc = cfma(E[r][1], S.Rst[1][c], acc);
      acc = cfma(E[r][2], S.Rst[2][c], acc);
      acc = cfma(E[r][3], S.Rst[3][c], acc);
      Rp[r] = acc;
    }

    const bool cinP = (c >= p0) && (c < p0 + 4);
    float2 Ecol[4];
    #pragma unroll
    for (int r = 0; r < 4; ++r) {
      float2 a = csel(cq & 1, E[r][1], E[r][0]);
      float2 b = csel(cq & 1, E[r][3], E[r][2]);
      Ecol[r] = csel(cq & 2, b, a);
    }
    float2 ra  = csel(w & 1, Rp[1], Rp[0]);
    float2 rb  = csel(w & 1, Rp[3], Rp[2]);
    float2 Rpw = csel(w & 2, rb, ra);
    float2 ea  = csel(w & 1, Ecol[1], Ecol[0]);
    float2 eb  = csel(w & 1, Ecol[3], Ecol[2]);
    float2 Ecw = csel(w & 2, eb, ea);
    float2 inPval = csel(cinP, Ecw, Rpw);

    #pragma unroll
    for (int qq = 0; qq < 16; ++qq) {
      int i = w + 4 * qq;
      const f4* fp = (const f4*)(&S.Cst[i][0]);   // broadcast (i uniform per wave)
      f4 f01 = fp[0], f23 = fp[1];
      float2 f0 = make_float2(f01.x, f01.y), f1 = make_float2(f01.z, f01.w);
      float2 f2 = make_float2(f23.x, f23.y), f3 = make_float2(f23.z, f23.w);
      float2 old = S.P[i][c];
      float2 g = old;
      g = cnfma(f0, Rp[0], g);
      g = cnfma(f1, Rp[1], g);
      g = cnfma(f2, Rp[2], g);
      g = cnfma(f3, Rp[3], g);
      float2 cp = cmul(f0, Ecol[0]);
      cp = cfma(f1, Ecol[1], cp);
      cp = cfma(f2, Ecol[2], cp);
      cp = cfma(f3, Ecol[3], cp);
      cp.x = -cp.x; cp.y = -cp.y;
      float2 other = csel(cinP, cp, g);
      float2 res   = csel(qq == ps, inPval, other);
      S.P[i][c] = res;
    }
    __syncthreads();
  }

  // SYMMETRIZED write-out: Pout[r][c] = 0.5*(P[r][c] + P[c][r]).
  int pbase = bb * kNB * kNB;
  #pragma unroll
  for (int q = 0; q < 16; ++q) {
    int e = q * 256 + t;
    int r = e >> 6, cc = e & 63;
    float2 v  = S.P[r][cc];
    float2 vt = S.P[cc][r];
    Pro[pbase + e] = 0.5f * (v.x + vt.x);
    Pio[pbase + e] = 0.5f * (v.y + vt.y);
  }
}

// Standalone pivotinv (used for k=0 of each chunk).
__global__ __launch_bounds__(256) void pivotinv_kernel(
    const float* __restrict__ Are, const float* __restrict__ Aim,
    float* __restrict__ Pro, float* __restrict__ Pio, int kstep)
{
  __shared__ PivSmem S;
  pivotinv_dev(S, Are, Aim, Pro, Pio, kstep, blockIdx.x, threadIdx.x);
}

// ---------------------------------------------------------------------------
// Row-fixup device body: A[k,ct] = Pinv @ A[k,ct]_old (ct != k); diag = Pinv.
// ---------------------------------------------------------------------------
__device__ void rowfix_dev(
    TileLds& L,
    float* __restrict__ Are, float* __restrict__ Aim,
    const float* __restrict__ Pr, const float* __restrict__ Pi,
    int kstep, int ct, int bb, int t)
{
  int pbase = bb * kNB * kNB;
  size_t rb = (size_t)bb * kN * kN + (size_t)(kstep * kNB) * kN + ct * kNB;
  if (ct == kstep) {
    for (int e = t; e < kNB * kNB / 4; e += 256) {
      int r = e >> 4, c4 = e & 15;
      *(f4*)(Are + rb + (size_t)r * kN + c4 * 4) = *(const f4*)(Pr + pbase + e * 4);
      *(f4*)(Aim + rb + (size_t)r * kN + c4 * 4) = *(const f4*)(Pi + pbase + e * 4);
    }
    return;
  }
  float cr[4][4] = {}, ci[4][4] = {};
  int r0 = (t >> 4) * 4, c0q = t & 15;

  stage_tiles(L, t, Pr + pbase, Pi + pbase, kNB,
              Are + rb, Aim + rb, kN);
  __syncthreads();

  f4 sar[2], sai[2], sbr[2], sbi[2];
  prefetch_regs(t, Pr + pbase + 32, Pi + pbase + 32, kNB,
                Are + rb + (size_t)32 * kN, Aim + rb + (size_t)32 * kN, kN,
                sar, sai, sbr, sbi);
  cgemm_tile(L, r0, c0q, cr, ci);
  __syncthreads();

  regs_to_lds(L, t, sar, sai, sbr, sbi);
  __syncthreads();
  cgemm_tile(L, r0, c0q, cr, ci);

  #pragma unroll
  for (int i = 0; i < 4; ++i) {
    size_t idx = rb + (size_t)(r0 + i) * kN + c0q * 4;
    *(f4*)(Are + idx) = (f4){cr[i][0], cr[i][1], cr[i][2], cr[i][3]};
    *(f4*)(Aim + idx) = (f4){ci[i][0], ci[i][1], ci[i][2], ci[i][3]};
  }
}

// ---------------------------------------------------------------------------
// Fused kernel: blocks x=0..15 -> rowfix(k); block x=16 -> pivotinv(k+1).
// ---------------------------------------------------------------------------
__global__ __launch_bounds__(256) void rowpiv_kernel(
    float* __restrict__ Are, float* __restrict__ Aim,
    const float* __restrict__ Prc, const float* __restrict__ Pic,
    float* __restrict__ Prn, float* __restrict__ Pin, int kstep)
{
  __shared__ FusedSmem S;
  int x = blockIdx.x, bb = blockIdx.y, t = threadIdx.x;
  if (x == kNT) {
    pivotinv_dev(S.piv, Are, Aim, Prn, Pin, kstep + 1, bb, t);
    return;
  }
  rowfix_dev(S.tile, Are, Aim, Prc, Pic, kstep, x, bb, t);
}

// ---------------------------------------------------------------------------
// Kernel 6: column block in place: A[rt,k] <- -(A[rt,k] @ Pinv)  (rt != k).
// ---------------------------------------------------------------------------
__global__ __launch_bounds__(256) void colgemm_kernel(
    float* __restrict__ Are, float* __restrict__ Aim,
    const float* __restrict__ Pr, const float* __restrict__ Pi, int kstep)
{
  int rt = blockIdx.x;
  if (rt == kstep) return;
  int bb = blockIdx.y, t = threadIdx.x;
  size_t abase = (size_t)bb * kN * kN + (size_t)(rt * kNB) * kN + kstep * kNB;
  int pbase = bb * kNB * kNB;
  __shared__ TileLds L;
  float cr[4][4] = {}, ci[4][4] = {};
  int r0 = (t >> 4) * 4, c0q = t & 15;

  stage_tiles(L, t, Are + abase, Aim + abase, kN,
              Pr + pbase, Pi + pbase, kNB);
  __syncthreads();

  f4 sar[2], sai[2], sbr[2], sbi[2];
  prefetch_regs(t, Are + abase + 32, Aim + abase + 32, kN,
                Pr + pbase + 32 * kNB, Pi + pbase + 32 * kNB, kNB,
                sar, sai, sbr, sbi);
  cgemm_tile(L, r0, c0q, cr, ci);
  __syncthreads();

  regs_to_lds(L, t, sar, sai, sbr, sbi);
  __syncthreads();
  cgemm_tile(L, r0, c0q, cr, ci);

  #pragma unroll
  for (int i = 0; i < 4; ++i) {
    size_t idx = abase + (size_t)(r0 + i) * kN + c0q * 4;
    *(f4*)(Are + idx) = (f4){-cr[i][0], -cr[i][1], -cr[i][2], -cr[i][3]};
    *(f4*)(Aim + idx) = (f4){-ci[i][0], -ci[i][1], -ci[i][2], -ci[i][3]};
  }
}

// ---------------------------------------------------------------------------
// Kernel 7 (round-10 proven): trailing update, LOWER TRIANGLE ONLY +
// symmetry mirror. Compute 120 lower pairs; mirror transposed eps-signed
// tile into the upper block via LDS bounce. Requires symmetrized Pinv.
// ---------------------------------------------------------------------------
__global__ __launch_bounds__(256) void update_kernel(
    float* __restrict__ Are, float* __restrict__ Aim, int kstep)
{
  int idx = blockIdx.x;            // 0..119 lower-triangle pair index
  int bb  = blockIdx.y;
  int t   = threadIdx.x;
  // decode idx -> (a, b) with a >= b over 15 indices (0..14)
  int a = (int)((sqrtf(8.0f * (float)idx + 1.0f) - 1.0f) * 0.5f);
  while ((a + 1) * (a + 2) / 2 <= idx) ++a;
  while (a * (a + 1) / 2 > idx) --a;
  int b = idx - a * (a + 1) / 2;
  int rt = a + (a >= kstep);
  int ct = b + (b >= kstep);

  size_t NNb     = (size_t)bb * kN * kN;
  size_t colbase = NNb + (size_t)(rt * kNB) * kN + kstep * kNB;
  size_t rowbase = NNb + (size_t)(kstep * kNB) * kN + ct * kNB;
  size_t cb      = NNb + (size_t)(rt * kNB) * kN + ct * kNB;
  __shared__ UpdSmem S;
  float cr[4][4] = {}, ci[4][4] = {};
  int r0 = (t >> 4) * 4, c0q = t & 15;

  stage_tiles(S.tile, t, Are + colbase, Aim + colbase, kN,
              Are + rowbase, Aim + rowbase, kN);
  __syncthreads();

  f4 sar[2], sai[2], sbr[2], sbi[2];
  prefetch_regs(t, Are + colbase + 32, Aim + colbase + 32, kN,
                Are + rowbase + (size_t)32 * kN,
                Aim + rowbase + (size_t)32 * kN, kN,
                sar, sai, sbr, sbi);
  cgemm_tile(S.tile, r0, c0q, cr, ci);
  __syncthreads();

  regs_to_lds(S.tile, t, sar, sai, sbr, sbi);
  __syncthreads();
  cgemm_tile(S.tile, r0, c0q, cr, ci);

  // RMW own (lower/diag) block, keep the new values for the mirror
  f4 vr4[4], vi4[4];
  #pragma unroll
  for (int i = 0; i < 4; ++i) {
    size_t gidx = cb + (size_t)(r0 + i) * kN + c0q * 4;
    f4 vr = *(const f4*)(Are + gidx);
    f4 vi = *(const f4*)(Aim + gidx);
    vr += (f4){cr[i][0], cr[i][1], cr[i][2], cr[i][3]};
    vi += (f4){ci[i][0], ci[i][1], ci[i][2], ci[i][3]};
    *(f4*)(Are + gidx) = vr;
    *(f4*)(Aim + gidx) = vi;
    vr4[i] = vr; vi4[i] = vi;
  }

  if (rt != ct) {
    float eps = ((rt < kstep) == (ct < kstep)) ? 1.0f : -1.0f;
    __syncthreads();                     // all tile-LDS reads complete
    #pragma unroll
    for (int i = 0; i < 4; ++i)
      #pragma unroll
      for (int j = 0; j < 4; ++j)
        S.M[c0q * 4 + j][r0 + i] =
            make_float2(eps * vr4[i][j], eps * vi4[i][j]);
    __syncthreads();
    size_t mb = NNb + (size_t)(ct * kNB) * kN + rt * kNB;   // mirror block
    #pragma unroll
    for (int q = 0; q < 4; ++q) {        // 1024 e-values: full 64 rows
      int e = q * 256 + t;
      int r = e >> 4, c4 = e & 15;
      float2 m0 = S.M[r][c4 * 4 + 0], m1 = S.M[r][c4 * 4 + 1];
      float2 m2 = S.M[r][c4 * 4 + 2], m3 = S.M[r][c4 * 4 + 3];
      *(f4*)(Are + mb + (size_t)r * kN + c4 * 4) = (f4){m0.x, m1.x, m2.x, m3.x};
      *(f4*)(Aim + mb + (size_t)r * kN + c4 * 4) = (f4){m0.y, m1.y, m2.y, m3.y};
    }
  }
}

// ---------------------------------------------------------------------------
// Kernel 9: |inv| -> f32 output (one chunk; out already offset by b0). f4 I/O.
// ---------------------------------------------------------------------------
__global__ __launch_bounds__(256) void abs_kernel(
    const float* __restrict__ Are, const float* __restrict__ Aim,
    float* __restrict__ outp)
{
  size_t e = (size_t)blockIdx.x * 256 + threadIdx.x;
  f4 re = *(const f4*)(Are + e * 4);
  f4 im = *(const f4*)(Aim + e * 4);
  f4 o;
  #pragma unroll
  for (int c = 0; c < 4; ++c) o[c] = sqrtf(re[c] * re[c] + im[c] * im[c]);
  *(f4*)(outp + e * 4) = o;
}

// ---------------------------------------------------------------------------
extern "C" void kernel_launch(void* const* d_in, const int* in_sizes, int n_in,
                              void* d_out, int out_size, void* d_ws, size_t ws_size,
                              hipStream_t stream)
{
  const float* gene  = (const float*)d_in[0];
  const float* coh   = (const float*)d_in[1];
  const float* emb   = (const float*)d_in[2];
  const float* gbase = (const float*)d_in[3];
  const float* ew1   = (const float*)d_in[4];
  const float* eb1   = (const float*)d_in[5];
  const float* ew2   = (const float*)d_in[6];
  const float* eb2   = (const float*)d_in[7];
  const float* ow1   = (const float*)d_in[8];
  const float* ob1   = (const float*)d_in[9];
  const float* ow2   = (const float*)d_in[10];
  const float* ob2   = (const float*)d_in[11];
  const float* Hm    = (const float*)d_in[12];

  float* out       = (float*)d_out;
  float* out_probs = out;                                  // 16*2
  float* out_dec   = out + 32;                             // 16*1024*64
  float* out_gamma = out + 32 + 1048576;                   // 16*1024
  float* out_prop  = out + 32 + 1048576 + 16384;           // 16*1024*1024

  // --- workspace sizing: chunk batches to fit ws_size -----------------------
  const size_t NN      = (size_t)kN * kN;                 // 1,048,576
  const size_t PB      = (size_t)kNB * kNB;               // 4096
  const size_t perB    = 2 * NN + 4 * PB;                 // A(re,im) + P parity x2
  const size_t fixedF  = NN + (size_t)kB * kN + 16 + (size_t)kB * 16 * 64;
  size_t availF = ws_size / 4;
  int chunk = 1;
  if (availF > fixedF + perB) {
    size_t c = (availF - fixedF) / perB;
    chunk = (int)(c > 16 ? 16 : c);
    if (chunk < 1) chunk = 1;
  }

  float* Are  = (float*)d_ws;
  float* Aim  = Are + (size_t)chunk * NN;
  float* Pr0  = Aim + (size_t)chunk * NN;
  float* Pi0  = Pr0 + (size_t)chunk * PB;
  float* Pr1  = Pi0 + (size_t)chunk * PB;
  float* Pi1  = Pr1 + (size_t)chunk * PB;
  float* Hs   = Pi1 + (size_t)chunk * PB;
  float* wsom = Hs  + NN;
  float* womm = wsom + (size_t)kB * kN;
  float* prt  = womm + 16;                                // 16*16*64 partials

  rows_kernel<<<kB * kN, 64, 0, stream>>>(gene, coh, gbase, ew1, eb1, ew2, eb2,
                                          ow1, ob1, ow2, ob2,
                                          out_dec, out_gamma, wsom);
  probs1_kernel<<<dim3(kB, 16), 256, 0, stream>>>(gene, prt);
  probs2_kernel<<<kB, 64, 0, stream>>>(prt, emb, out_probs);
  omean_kernel<<<kB, 256, 0, stream>>>(wsom, womm);
  hs_kernel<<<(kN * kN) / 256, 256, 0, stream>>>(Hm, Hs);

  for (int b0 = 0; b0 < kB; b0 += chunk) {
    int c = (b0 + chunk <= kB) ? chunk : (kB - b0);
    build_kernel<<<dim3((kN * kN) / 1024, c), 256, 0, stream>>>(Hs, womm, Are, Aim, b0);
    pivotinv_kernel<<<c, 256, 0, stream>>>(Are, Aim, Pr0, Pi0, 0);
    for (int k = 0; k < kNT; ++k) {
      float* Prc = (k & 1) ? Pr1 : Pr0;
      float* Pic = (k & 1) ? Pi1 : Pi0;
      float* Prn = (k & 1) ? Pr0 : Pr1;
      float* Pin = (k & 1) ? Pi0 : Pi1;
      colgemm_kernel<<<dim3(kNT, c), 256, 0, stream>>>(Are, Aim, Prc, Pic, k);
      update_kernel<<<dim3(120, c), 256, 0, stream>>>(Are, Aim, k);
      int gx = (k < kNT - 1) ? (kNT + 1) : kNT;
      rowpiv_kernel<<<dim3(gx, c), 256, 0, stream>>>(Are, Aim, Prc, Pic, Prn, Pin, k);
    }
    abs_kernel<<<c * (kN * kN / 1024), 256, 0, stream>>>(
        Are, Aim, out_prop + (size_t)b0 * NN);
  }
}

// Round 13
// 2162.196 us; speedup vs baseline: 1.4794x; 1.0606x over previous
//
#include <hip/hip_runtime.h>
#include <hip/hip_bf16.h>

constexpr int kB  = 16;
constexpr int kN  = 1024;
constexpr int kH  = 64;
constexpr int kNB = 64;
constexpr int kNT = 16;   // kN / kNB

typedef float f4 __attribute__((ext_vector_type(4)));

// complex helpers ------------------------------------------------------------
__device__ __forceinline__ float2 cmul(float2 a, float2 b) {
  return make_float2(a.x * b.x - a.y * b.y, a.x * b.y + a.y * b.x);
}
__device__ __forceinline__ float2 cfma(float2 a, float2 b, float2 acc) {   // acc + a*b
  acc.x = fmaf(a.x, b.x, fmaf(-a.y, b.y, acc.x));
  acc.y = fmaf(a.x, b.y, fmaf( a.y, b.x, acc.y));
  return acc;
}
__device__ __forceinline__ float2 cnfma(float2 a, float2 b, float2 acc) {  // acc - a*b
  acc.x = fmaf(-a.x, b.x, fmaf( a.y, b.y, acc.x));
  acc.y = fmaf(-a.x, b.y, fmaf(-a.y, b.x, acc.y));
  return acc;
}
__device__ __forceinline__ float2 cinv(float2 p) {
  float d = 1.0f / (p.x * p.x + p.y * p.y);
  return make_float2(p.x * d, -p.y * d);
}
__device__ __forceinline__ float2 csel(bool c, float2 a, float2 b) {
  return c ? a : b;
}

// ---------------------------------------------------------------------------
// LDS tile layout for 64x64 complex block-GEMMs. 35840 B.
// ---------------------------------------------------------------------------
struct TileLds {
  f4 Ar[64][9];
  f4 Ai[64][9];
  f4 Br[32][17];
  f4 Bi[32][17];
};

// Pivot-inverse LDS: P + single-buffered panels. 37376 B.
struct PivSmem {
  float2 P[kNB][kNB + 1];
  float2 Cst[kNB][4];    // col panel (old values)
  float2 Rst[4][kNB];    // row panel (old values)
};

union FusedSmem {
  TileLds tile;
  PivSmem piv;
};

// update_kernel LDS: GEMM tile, then reused as transpose bounce for mirror.
// M row stride 67 float2 (134 floats, 6 mod 32 banks): round-12 counters
// showed 1.29M bank-conflict cycles with stride 66 (132 = 4 mod 32 -> the
// 16 row-writing lanes landed on 2 bank groups, 8-way). 67 -> 2-way (free).
union UpdSmem {
  TileLds tile;
  float2  M[64][67];     // 34304 B <= 35840
};

// Stage one K=32 chunk directly global -> LDS (chunk 0 path).
__device__ __forceinline__ void stage_tiles(
    TileLds& L, int t,
    const float* __restrict__ Agr, const float* __restrict__ Agi, int astride,
    const float* __restrict__ Bgr, const float* __restrict__ Bgi, int bstride)
{
  #pragma unroll
  for (int q = 0; q < 2; ++q) {
    int e = q * 256 + t;
    int ra = e >> 3, ca = e & 7;        // A: 64 x 8 f4
    L.Ar[ra][ca] = *(const f4*)(Agr + (size_t)ra * astride + ca * 4);
    L.Ai[ra][ca] = *(const f4*)(Agi + (size_t)ra * astride + ca * 4);
    int rb = e >> 4, cb = e & 15;       // B: 32 x 16 f4
    L.Br[rb][cb] = *(const f4*)(Bgr + (size_t)rb * bstride + cb * 4);
    L.Bi[rb][cb] = *(const f4*)(Bgi + (size_t)rb * bstride + cb * 4);
  }
}

// T14 split: issue chunk-1 global loads into regs ...
__device__ __forceinline__ void prefetch_regs(
    int t,
    const float* __restrict__ Agr, const float* __restrict__ Agi, int astride,
    const float* __restrict__ Bgr, const float* __restrict__ Bgi, int bstride,
    f4 (&sar)[2], f4 (&sai)[2], f4 (&sbr)[2], f4 (&sbi)[2])
{
  #pragma unroll
  for (int q = 0; q < 2; ++q) {
    int e = q * 256 + t;
    int ra = e >> 3, ca = e & 7;
    sar[q] = *(const f4*)(Agr + (size_t)ra * astride + ca * 4);
    sai[q] = *(const f4*)(Agi + (size_t)ra * astride + ca * 4);
    int rb = e >> 4, cb = e & 15;
    sbr[q] = *(const f4*)(Bgr + (size_t)rb * bstride + cb * 4);
    sbi[q] = *(const f4*)(Bgi + (size_t)rb * bstride + cb * 4);
  }
}

// ... then write them to LDS after the barrier.
__device__ __forceinline__ void regs_to_lds(
    TileLds& L, int t,
    const f4 (&sar)[2], const f4 (&sai)[2],
    const f4 (&sbr)[2], const f4 (&sbi)[2])
{
  #pragma unroll
  for (int q = 0; q < 2; ++q) {
    int e = q * 256 + t;
    int ra = e >> 3, ca = e & 7;
    L.Ar[ra][ca] = sar[q]; L.Ai[ra][ca] = sai[q];
    int rb = e >> 4, cb = e & 15;
    L.Br[rb][cb] = sbr[q]; L.Bi[rb][cb] = sbi[q];
  }
}

__device__ __forceinline__ void cgemm_tile(
    const TileLds& L, int r0, int c0q, float (&cr)[4][4], float (&ci)[4][4])
{
  #pragma unroll 2
  for (int mq = 0; mq < 8; ++mq) {
    f4 ar[4], ai[4];
    #pragma unroll
    for (int i = 0; i < 4; ++i) {
      ar[i] = L.Ar[r0 + i][mq];
      ai[i] = L.Ai[r0 + i][mq];
    }
    #pragma unroll
    for (int mm = 0; mm < 4; ++mm) {
      f4 br = L.Br[mq * 4 + mm][c0q];
      f4 bi = L.Bi[mq * 4 + mm][c0q];
      #pragma unroll
      for (int i = 0; i < 4; ++i) {
        float a_r = ar[i][mm], a_i = ai[i][mm];
        #pragma unroll
        for (int j = 0; j < 4; ++j) {
          cr[i][j] = fmaf(a_r, br[j], fmaf(-a_i, bi[j], cr[i][j]));
          ci[i][j] = fmaf(a_r, bi[j], fmaf( a_i, br[j], ci[i][j]));
        }
      }
    }
  }
}

// ---------------------------------------------------------------------------
// Kernel 1: per-row MLPs (env & omega), gamma, decohered, omega staging.
// ---------------------------------------------------------------------------
__global__ __launch_bounds__(64) void rows_kernel(
    const float* __restrict__ gene, const float* __restrict__ coh,
    const float* __restrict__ gbase,
    const float* __restrict__ ew1, const float* __restrict__ eb1,
    const float* __restrict__ ew2, const float* __restrict__ eb2,
    const float* __restrict__ ow1, const float* __restrict__ ob1,
    const float* __restrict__ ow2, const float* __restrict__ ob2,
    float* __restrict__ out_dec, float* __restrict__ out_gamma,
    float* __restrict__ ws_omega)
{
  int row = blockIdx.x;          // b*kN + n
  int n   = row & (kN - 1);
  int t   = threadIdx.x;         // 0..63
  float g = gene[(size_t)row * kH + t];

  float s = g;
  #pragma unroll
  for (int off = 32; off >= 1; off >>= 1) s += __shfl_xor(s, off);
  float classical = s * (1.0f / kH);

  bool isEnv = t < 32;
  int  j     = isEnv ? t : (t - 32);
  const float* w1 = isEnv ? ew1 : ow1;
  float acc = isEnv ? eb1[j] : ob1[j];
  #pragma unroll
  for (int h = 0; h < kH; ++h) {
    float gh = __shfl(g, h);
    acc = fmaf(gh, w1[h * 32 + j], acc);
  }
  float sl   = acc * (1.0f / (1.0f + expf(-acc)));   // silu
  float term = sl * (isEnv ? ew2[j] : ow2[j]);
  #pragma unroll
  for (int off = 16; off >= 1; off >>= 1) term += __shfl_xor(term, off);
  float env_sum = __shfl(term, 0);
  float om_sum  = __shfl(term, 32);

  float env   = 1.0f / (1.0f + expf(-(env_sum + eb2[0])));
  float gamma = (1.0f / (1.0f + expf(-gbase[n]))) * (1.0f + env);

  float dec = (1.0f - gamma) * coh[(size_t)row * kH + t] + gamma * classical;
  out_dec[(size_t)row * kH + t] = dec;
  if (t == 0)  out_gamma[row] = gamma;
  if (t == 63) ws_omega[row]  = om_sum + ob2[0];
}

// ---------------------------------------------------------------------------
// Kernel 2 (two-stage): cell mean + cosine-sim softmax -> state_probs.
// ---------------------------------------------------------------------------
__global__ __launch_bounds__(256) void probs1_kernel(
    const float* __restrict__ gene, float* __restrict__ prt)
{
  __shared__ float red[256];
  int b = blockIdx.x, s = blockIdx.y, t = threadIdx.x;
  int h = t & 63, q = t >> 6;
  const float* gp = gene + ((size_t)b * kN + s * 64 + q * 16) * kH + h;
  float sum = 0.0f;
  #pragma unroll
  for (int i = 0; i < 16; ++i) sum += gp[(size_t)i * kH];
  red[t] = sum;
  __syncthreads();
  if (t < 64)
    prt[(b * 16 + s) * 64 + t] = red[t] + red[t + 64] + red[t + 128] + red[t + 192];
}

__global__ __launch_bounds__(64) void probs2_kernel(
    const float* __restrict__ prt, const float* __restrict__ emb,
    float* __restrict__ outp)
{
  __shared__ float cell[64];
  int b = blockIdx.x, t = threadIdx.x;
  float s = 0.0f;
  #pragma unroll
  for (int i = 0; i < 16; ++i) s += prt[(b * 16 + i) * 64 + t];
  cell[t] = s * (1.0f / kN);
  __syncthreads();
  if (t == 0) {
    float nc = 0.0f;
    for (int x = 0; x < 64; ++x) nc += cell[x] * cell[x];
    nc = fmaxf(sqrtf(nc), 1e-12f);
    float l[2];
    for (int s2 = 0; s2 < 2; ++s2) {
      float ne = 0.0f, dot = 0.0f;
      for (int x = 0; x < 64; ++x) { float e = emb[s2 * 64 + x]; ne += e * e; }
      ne = fmaxf(sqrtf(ne), 1e-12f);
      for (int x = 0; x < 64; ++x) dot += (cell[x] / nc) * (emb[s2 * 64 + x] / ne);
      l[s2] = dot * 10.0f;   // /0.1
    }
    float m  = fmaxf(l[0], l[1]);
    float e0 = expf(l[0] - m), e1 = expf(l[1] - m);
    outp[b * 2 + 0] = e0 / (e0 + e1);
    outp[b * 2 + 1] = e1 / (e0 + e1);
  }
}

// ---------------------------------------------------------------------------
// Kernel 3: omega_mean per batch.
// ---------------------------------------------------------------------------
__global__ __launch_bounds__(256) void omean_kernel(
    const float* __restrict__ om, float* __restrict__ omm)
{
  __shared__ float red[256];
  int b = blockIdx.x, t = threadIdx.x;
  float s = om[b * kN + t] + om[b * kN + t + 256] + om[b * kN + t + 512] + om[b * kN + t + 768];
  red[t] = s;
  __syncthreads();
  for (int off = 128; off >= 1; off >>= 1) {
    if (t < off) red[t] += red[t + off];
    __syncthreads();
  }
  if (t == 0) omm[b] = red[0] * (1.0f / kN);
}

// ---------------------------------------------------------------------------
// Kernel 4a: H_sym (fp32).  4b: A = w*I - H_sym (+ i*eta on diag), f4 stores.
// ---------------------------------------------------------------------------
__global__ __launch_bounds__(256) void hs_kernel(
    const float* __restrict__ Hm, float* __restrict__ Hs)
{
  int idx = blockIdx.x * 256 + threadIdx.x;
  int i = idx >> 10, j = idx & 1023;
  Hs[idx] = 0.5f * (Hm[i * kN + j] + Hm[j * kN + i]);
}

__global__ __launch_bounds__(256) void build_kernel(
    const float* __restrict__ Hs, const float* __restrict__ omm,
    float* __restrict__ Are, float* __restrict__ Aim, int b0)
{
  int bb = blockIdx.y;
  int e = blockIdx.x * 256 + threadIdx.x;     // f4 index into NN/4
  int i = e >> 8, j4 = e & 255;               // row, f4 column
  float wr = omm[b0 + bb];
  f4 h = *(const f4*)(Hs + (size_t)e * 4);
  f4 re, im;
  #pragma unroll
  for (int c = 0; c < 4; ++c) {               // branchless diag, static idx
    bool d = (j4 * 4 + c == i);
    re[c] = (d ? wr : 0.0f) - h[c];
    im[c] = d ? 0.01f : 0.0f;
  }
  *(f4*)(Are + (size_t)bb * kN * kN + (size_t)e * 4) = re;
  *(f4*)(Aim + (size_t)bb * kN * kN + (size_t)e * 4) = im;
}

// ---------------------------------------------------------------------------
// Pivot-block inverse device body: rank-4 blocked Gauss-Jordan, symmetrized
// output (round-10 proven; exact E symmetry required by the mirror scheme).
// ---------------------------------------------------------------------------
__device__ void pivotinv_dev(
    PivSmem& S,
    const float* __restrict__ Are, const float* __restrict__ Aim,
    float* __restrict__ Pro, float* __restrict__ Pio, int kstep, int bb, int t)
{
  size_t base = (size_t)bb * kN * kN + (size_t)(kstep * kNB) * kN + kstep * kNB;

  #pragma unroll
  for (int q = 0; q < 16; ++q) {
    int e = q * 256 + t;
    int r = e >> 6, c = e & 63;
    S.P[r][c] = make_float2(Are[base + (size_t)r * kN + c],
                            Aim[base + (size_t)r * kN + c]);
  }
  __syncthreads();

  const int c = t & 63;        // thread-fixed column
  const int w = t >> 6;        // 0..3
  const int cq = c & 3;        // panel-local column when cinP (p0 % 4 == 0)

  for (int ps = 0; ps < 16; ++ps) {
    const int p0 = ps * 4;
    S.Cst[t >> 2][t & 3]  = S.P[t >> 2][p0 + (t & 3)];
    S.Rst[t >> 6][t & 63] = S.P[p0 + (t >> 6)][t & 63];
    __syncthreads();

    float2 E[4][4];
    #pragma unroll
    for (int r = 0; r < 4; ++r)
      #pragma unroll
      for (int q = 0; q < 4; ++q) E[r][q] = S.Rst[r][p0 + q];
    #pragma unroll
    for (int s4 = 0; s4 < 4; ++s4) {
      float2 ip = cinv(E[s4][s4]);
      #pragma unroll
      for (int cc = 0; cc < 4; ++cc)
        if (cc != s4) E[s4][cc] = cmul(E[s4][cc], ip);
      #pragma unroll
      for (int i = 0; i < 4; ++i)
        if (i != s4) {
          float2 f = E[i][s4];
          #pragma unroll
          for (int cc = 0; cc < 4; ++cc)
            if (cc != s4) E[i][cc] = cnfma(f, E[s4][cc], E[i][cc]);
          E[i][s4] = cmul(make_float2(-f.x, -f.y), ip);
        }
      E[s4][s4] = ip;
    }

    float2 Rp[4];
    #pragma unroll
    for (int r = 0; r < 4; ++r) {
      float2 acc = cmul(E[r][0], S.Rst[0][c]);
      acc = cfma(E[r][1], S.Rst[1][c], acc);
      acc = cfma(E[r][2], S.Rst[2][c], acc);
      acc = cfma(E[r][3], S.Rst[3][c], acc);
      Rp[r] = acc;
    }

    const bool cinP = (c >= p0) && (c < p0 + 4);
    float2 Ecol[4];
    #pragma unroll
    for (int r = 0; r < 4; ++r) {
      float2 a = csel(cq & 1, E[r][1], E[r][0]);
      float2 b = csel(cq & 1, E[r][3], E[r][2]);
      Ecol[r] = csel(cq & 2, b, a);
    }
    float2 ra  = csel(w & 1, Rp[1], Rp[0]);
    float2 rb  = csel(w & 1, Rp[3], Rp[2]);
    float2 Rpw = csel(w & 2, rb, ra);
    float2 ea  = csel(w & 1, Ecol[1], Ecol[0]);
    float2 eb  = csel(w & 1, Ecol[3], Ecol[2]);
    float2 Ecw = csel(w & 2, eb, ea);
    float2 inPval = csel(cinP, Ecw, Rpw);

    #pragma unroll
    for (int qq = 0; qq < 16; ++qq) {
      int i = w + 4 * qq;
      const f4* fp = (const f4*)(&S.Cst[i][0]);   // broadcast (i uniform per wave)
      f4 f01 = fp[0], f23 = fp[1];
      float2 f0 = make_float2(f01.x, f01.y), f1 = make_float2(f01.z, f01.w);
      float2 f2 = make_float2(f23.x, f23.y), f3 = make_float2(f23.z, f23.w);
      float2 old = S.P[i][c];
      float2 g = old;
      g = cnfma(f0, Rp[0], g);
      g = cnfma(f1, Rp[1], g);
      g = cnfma(f2, Rp[2], g);
      g = cnfma(f3, Rp[3], g);
      float2 cp = cmul(f0, Ecol[0]);
      cp = cfma(f1, Ecol[1], cp);
      cp = cfma(f2, Ecol[2], cp);
      cp = cfma(f3, Ecol[3], cp);
      cp.x = -cp.x; cp.y = -cp.y;
      float2 other = csel(cinP, cp, g);
      float2 res   = csel(qq == ps, inPval, other);
      S.P[i][c] = res;
    }
    __syncthreads();
  }

  // SYMMETRIZED write-out: Pout[r][c] = 0.5*(P[r][c] + P[c][r]).
  int pbase = bb * kNB * kNB;
  #pragma unroll
  for (int q = 0; q < 16; ++q) {
    int e = q * 256 + t;
    int r = e >> 6, cc = e & 63;
    float2 v  = S.P[r][cc];
    float2 vt = S.P[cc][r];
    Pro[pbase + e] = 0.5f * (v.x + vt.x);
    Pio[pbase + e] = 0.5f * (v.y + vt.y);
  }
}

// Standalone pivotinv (used for k=0 of each chunk).
__global__ __launch_bounds__(256) void pivotinv_kernel(
    const float* __restrict__ Are, const float* __restrict__ Aim,
    float* __restrict__ Pro, float* __restrict__ Pio, int kstep)
{
  __shared__ PivSmem S;
  pivotinv_dev(S, Are, Aim, Pro, Pio, kstep, blockIdx.x, threadIdx.x);
}

// ---------------------------------------------------------------------------
// Row-fixup device body: A[k,ct] = Pinv @ A[k,ct]_old (ct != k); diag = Pinv.
// ---------------------------------------------------------------------------
__device__ void rowfix_dev(
    TileLds& L,
    float* __restrict__ Are, float* __restrict__ Aim,
    const float* __restrict__ Pr, const float* __restrict__ Pi,
    int kstep, int ct, int bb, int t)
{
  int pbase = bb * kNB * kNB;
  size_t rb = (size_t)bb * kN * kN + (size_t)(kstep * kNB) * kN + ct * kNB;
  if (ct == kstep) {
    for (int e = t; e < kNB * kNB / 4; e += 256) {
      int r = e >> 4, c4 = e & 15;
      *(f4*)(Are + rb + (size_t)r * kN + c4 * 4) = *(const f4*)(Pr + pbase + e * 4);
      *(f4*)(Aim + rb + (size_t)r * kN + c4 * 4) = *(const f4*)(Pi + pbase + e * 4);
    }
    return;
  }
  float cr[4][4] = {}, ci[4][4] = {};
  int r0 = (t >> 4) * 4, c0q = t & 15;

  stage_tiles(L, t, Pr + pbase, Pi + pbase, kNB,
              Are + rb, Aim + rb, kN);
  __syncthreads();

  f4 sar[2], sai[2], sbr[2], sbi[2];
  prefetch_regs(t, Pr + pbase + 32, Pi + pbase + 32, kNB,
                Are + rb + (size_t)32 * kN, Aim + rb + (size_t)32 * kN, kN,
                sar, sai, sbr, sbi);
  cgemm_tile(L, r0, c0q, cr, ci);
  __syncthreads();

  regs_to_lds(L, t, sar, sai, sbr, sbi);
  __syncthreads();
  cgemm_tile(L, r0, c0q, cr, ci);

  #pragma unroll
  for (int i = 0; i < 4; ++i) {
    size_t idx = rb + (size_t)(r0 + i) * kN + c0q * 4;
    *(f4*)(Are + idx) = (f4){cr[i][0], cr[i][1], cr[i][2], cr[i][3]};
    *(f4*)(Aim + idx) = (f4){ci[i][0], ci[i][1], ci[i][2], ci[i][3]};
  }
}

// ---------------------------------------------------------------------------
// Fused kernel: blocks x=0..15 -> rowfix(k); block x=16 -> pivotinv(k+1).
// ---------------------------------------------------------------------------
__global__ __launch_bounds__(256) void rowpiv_kernel(
    float* __restrict__ Are, float* __restrict__ Aim,
    const float* __restrict__ Prc, const float* __restrict__ Pic,
    float* __restrict__ Prn, float* __restrict__ Pin, int kstep)
{
  __shared__ FusedSmem S;
  int x = blockIdx.x, bb = blockIdx.y, t = threadIdx.x;
  if (x == kNT) {
    pivotinv_dev(S.piv, Are, Aim, Prn, Pin, kstep + 1, bb, t);
    return;
  }
  rowfix_dev(S.tile, Are, Aim, Prc, Pic, kstep, x, bb, t);
}

// ---------------------------------------------------------------------------
// Kernel 6: column block in place: A[rt,k] <- -(A[rt,k] @ Pinv)  (rt != k).
// ---------------------------------------------------------------------------
__global__ __launch_bounds__(256) void colgemm_kernel(
    float* __restrict__ Are, float* __restrict__ Aim,
    const float* __restrict__ Pr, const float* __restrict__ Pi, int kstep)
{
  int rt = blockIdx.x;
  if (rt == kstep) return;
  int bb = blockIdx.y, t = threadIdx.x;
  size_t abase = (size_t)bb * kN * kN + (size_t)(rt * kNB) * kN + kstep * kNB;
  int pbase = bb * kNB * kNB;
  __shared__ TileLds L;
  float cr[4][4] = {}, ci[4][4] = {};
  int r0 = (t >> 4) * 4, c0q = t & 15;

  stage_tiles(L, t, Are + abase, Aim + abase, kN,
              Pr + pbase, Pi + pbase, kNB);
  __syncthreads();

  f4 sar[2], sai[2], sbr[2], sbi[2];
  prefetch_regs(t, Are + abase + 32, Aim + abase + 32, kN,
                Pr + pbase + 32 * kNB, Pi + pbase + 32 * kNB, kNB,
                sar, sai, sbr, sbi);
  cgemm_tile(L, r0, c0q, cr, ci);
  __syncthreads();

  regs_to_lds(L, t, sar, sai, sbr, sbi);
  __syncthreads();
  cgemm_tile(L, r0, c0q, cr, ci);

  #pragma unroll
  for (int i = 0; i < 4; ++i) {
    size_t idx = abase + (size_t)(r0 + i) * kN + c0q * 4;
    *(f4*)(Are + idx) = (f4){-cr[i][0], -cr[i][1], -cr[i][2], -cr[i][3]};
    *(f4*)(Aim + idx) = (f4){-ci[i][0], -ci[i][1], -ci[i][2], -ci[i][3]};
  }
}

// ---------------------------------------------------------------------------
// Kernel 7 (v7): trailing update, LOWER TRIANGLE ONLY + symmetry mirror.
// Round-13 deltas vs proven v6: (a) M padded 66->67 (kills 8-way mirror
// bank conflict); (b) T14 C-tile prefetch -- issue the 8 C-loads after the
// chunk-1 LDS write barrier so ~900cy HBM latency hides under compute-1.
// ---------------------------------------------------------------------------
__global__ __launch_bounds__(256) void update_kernel(
    float* __restrict__ Are, float* __restrict__ Aim, int kstep)
{
  int idx = blockIdx.x;            // 0..119 lower-triangle pair index
  int bb  = blockIdx.y;
  int t   = threadIdx.x;
  // decode idx -> (a, b) with a >= b over 15 indices (0..14)
  int a = (int)((sqrtf(8.0f * (float)idx + 1.0f) - 1.0f) * 0.5f);
  while ((a + 1) * (a + 2) / 2 <= idx) ++a;
  while (a * (a + 1) / 2 > idx) --a;
  int b = idx - a * (a + 1) / 2;
  int rt = a + (a >= kstep);
  int ct = b + (b >= kstep);

  size_t NNb     = (size_t)bb * kN * kN;
  size_t colbase = NNb + (size_t)(rt * kNB) * kN + kstep * kNB;
  size_t rowbase = NNb + (size_t)(kstep * kNB) * kN + ct * kNB;
  size_t cb      = NNb + (size_t)(rt * kNB) * kN + ct * kNB;
  __shared__ UpdSmem S;
  float cr[4][4] = {}, ci[4][4] = {};
  int r0 = (t >> 4) * 4, c0q = t & 15;

  stage_tiles(S.tile, t, Are + colbase, Aim + colbase, kN,
              Are + rowbase, Aim + rowbase, kN);
  __syncthreads();

  f4 sar[2], sai[2], sbr[2], sbi[2];
  prefetch_regs(t, Are + colbase + 32, Aim + colbase + 32, kN,
                Are + rowbase + (size_t)32 * kN,
                Aim + rowbase + (size_t)32 * kN, kN,
                sar, sai, sbr, sbi);
  cgemm_tile(S.tile, r0, c0q, cr, ci);
  __syncthreads();

  regs_to_lds(S.tile, t, sar, sai, sbr, sbi);
  __syncthreads();

  // T14: prefetch own C tile; latency hides under compute-1 (~2000 cy).
  f4 cre[4], cim[4];
  #pragma unroll
  for (int i = 0; i < 4; ++i) {
    size_t gidx = cb + (size_t)(r0 + i) * kN + c0q * 4;
    cre[i] = *(const f4*)(Are + gidx);
    cim[i] = *(const f4*)(Aim + gidx);
  }

  cgemm_tile(S.tile, r0, c0q, cr, ci);

  // RMW own (lower/diag) block, keep the new values for the mirror
  f4 vr4[4], vi4[4];
  #pragma unroll
  for (int i = 0; i < 4; ++i) {
    size_t gidx = cb + (size_t)(r0 + i) * kN + c0q * 4;
    f4 vr = cre[i] + (f4){cr[i][0], cr[i][1], cr[i][2], cr[i][3]};
    f4 vi = cim[i] + (f4){ci[i][0], ci[i][1], ci[i][2], ci[i][3]};
    *(f4*)(Are + gidx) = vr;
    *(f4*)(Aim + gidx) = vi;
    vr4[i] = vr; vi4[i] = vi;
  }

  if (rt != ct) {
    float eps = ((rt < kstep) == (ct < kstep)) ? 1.0f : -1.0f;
    __syncthreads();                     // all tile-LDS reads complete
    #pragma unroll
    for (int i = 0; i < 4; ++i)
      #pragma unroll
      for (int j = 0; j < 4; ++j)
        S.M[c0q * 4 + j][r0 + i] =
            make_float2(eps * vr4[i][j], eps * vi4[i][j]);
    __syncthreads();
    size_t mb = NNb + (size_t)(ct * kNB) * kN + rt * kNB;   // mirror block
    #pragma unroll
    for (int q = 0; q < 4; ++q) {        // 1024 e-values: full 64 rows
      int e = q * 256 + t;
      int r = e >> 4, c4 = e & 15;
      float2 m0 = S.M[r][c4 * 4 + 0], m1 = S.M[r][c4 * 4 + 1];
      float2 m2 = S.M[r][c4 * 4 + 2], m3 = S.M[r][c4 * 4 + 3];
      *(f4*)(Are + mb + (size_t)r * kN + c4 * 4) = (f4){m0.x, m1.x, m2.x, m3.x};
      *(f4*)(Aim + mb + (size_t)r * kN + c4 * 4) = (f4){m0.y, m1.y, m2.y, m3.y};
    }
  }
}

// ---------------------------------------------------------------------------
// Kernel 9: |inv| -> f32 output (one chunk; out already offset by b0). f4 I/O.
// ---------------------------------------------------------------------------
__global__ __launch_bounds__(256) void abs_kernel(
    const float* __restrict__ Are, const float* __restrict__ Aim,
    float* __restrict__ outp)
{
  size_t e = (size_t)blockIdx.x * 256 + threadIdx.x;
  f4 re = *(const f4*)(Are + e * 4);
  f4 im = *(const f4*)(Aim + e * 4);
  f4 o;
  #pragma unroll
  for (int c = 0; c < 4; ++c) o[c] = sqrtf(re[c] * re[c] + im[c] * im[c]);
  *(f4*)(outp + e * 4) = o;
}

// ---------------------------------------------------------------------------
extern "C" void kernel_launch(void* const* d_in, const int* in_sizes, int n_in,
                              void* d_out, int out_size, void* d_ws, size_t ws_size,
                              hipStream_t stream)
{
  const float* gene  = (const float*)d_in[0];
  const float* coh   = (const float*)d_in[1];
  const float* emb   = (const float*)d_in[2];
  const float* gbase = (const float*)d_in[3];
  const float* ew1   = (const float*)d_in[4];
  const float* eb1   = (const float*)d_in[5];
  const float* ew2   = (const float*)d_in[6];
  const float* eb2   = (const float*)d_in[7];
  const float* ow1   = (const float*)d_in[8];
  const float* ob1   = (const float*)d_in[9];
  const float* ow2   = (const float*)d_in[10];
  const float* ob2   = (const float*)d_in[11];
  const float* Hm    = (const float*)d_in[12];

  float* out       = (float*)d_out;
  float* out_probs = out;                                  // 16*2
  float* out_dec   = out + 32;                             // 16*1024*64
  float* out_gamma = out + 32 + 1048576;                   // 16*1024
  float* out_prop  = out + 32 + 1048576 + 16384;           // 16*1024*1024

  // --- workspace sizing: chunk batches to fit ws_size -----------------------
  const size_t NN      = (size_t)kN * kN;                 // 1,048,576
  const size_t PB      = (size_t)kNB * kNB;               // 4096
  const size_t perB    = 2 * NN + 4 * PB;                 // A(re,im) + P parity x2
  const size_t fixedF  = NN + (size_t)kB * kN + 16 + (size_t)kB * 16 * 64;
  size_t availF = ws_size / 4;
  int chunk = 1;
  if (availF > fixedF + perB) {
    size_t c = (availF - fixedF) / perB;
    chunk = (int)(c > 16 ? 16 : c);
    if (chunk < 1) chunk = 1;
  }

  float* Are  = (float*)d_ws;
  float* Aim  = Are + (size_t)chunk * NN;
  float* Pr0  = Aim + (size_t)chunk * NN;
  float* Pi0  = Pr0 + (size_t)chunk * PB;
  float* Pr1  = Pi0 + (size_t)chunk * PB;
  float* Pi1  = Pr1 + (size_t)chunk * PB;
  float* Hs   = Pi1 + (size_t)chunk * PB;
  float* wsom = Hs  + NN;
  float* womm = wsom + (size_t)kB * kN;
  float* prt  = womm + 16;                                // 16*16*64 partials

  rows_kernel<<<kB * kN, 64, 0, stream>>>(gene, coh, gbase, ew1, eb1, ew2, eb2,
                                          ow1, ob1, ow2, ob2,
                                          out_dec, out_gamma, wsom);
  probs1_kernel<<<dim3(kB, 16), 256, 0, stream>>>(gene, prt);
  probs2_kernel<<<kB, 64, 0, stream>>>(prt, emb, out_probs);
  omean_kernel<<<kB, 256, 0, stream>>>(wsom, womm);
  hs_kernel<<<(kN * kN) / 256, 256, 0, stream>>>(Hm, Hs);

  for (int b0 = 0; b0 < kB; b0 += chunk) {
    int c = (b0 + chunk <= kB) ? chunk : (kB - b0);
    build_kernel<<<dim3((kN * kN) / 1024, c), 256, 0, stream>>>(Hs, womm, Are, Aim, b0);
    pivotinv_kernel<<<c, 256, 0, stream>>>(Are, Aim, Pr0, Pi0, 0);
    for (int k = 0; k < kNT; ++k) {
      float* Prc = (k & 1) ? Pr1 : Pr0;
      float* Pic = (k & 1) ? Pi1 : Pi0;
      float* Prn = (k & 1) ? Pr0 : Pr1;
      float* Pin = (k & 1) ? Pi0 : Pi1;
      colgemm_kernel<<<dim3(kNT, c), 256, 0, stream>>>(Are, Aim, Prc, Pic, k);
      update_kernel<<<dim3(120, c), 256, 0, stream>>>(Are, Aim, k);
      int gx = (k < kNT - 1) ? (kNT + 1) : kNT;
      rowpiv_kernel<<<dim3(gx, c), 256, 0, stream>>>(Are, Aim, Prc, Pic, Prn, Pin, k);
    }
    abs_kernel<<<c * (kN * kN / 1024), 256, 0, stream>>>(
        Are, Aim, out_prop + (size_t)b0 * NN);
  }
}